// Round 4
// baseline (447.242 us; speedup 1.0000x reference)
//
#include <hip/hip_runtime.h>

// R11: dual-pipeline. R10 post-mortem: with 1 wave/SIMD, ~600 of ~850
// cyc/step is exposed latency (ds_read ~120, MFMA->VALU hazards, ds_write+
// lgkm+barrier); x-prefetch drain was never the issue. Fix: 2 independent
// 4-seq LSTM groups per block (GSEQ=8, 64 blocks), SAME weight fragments,
// interleaved in the same waves: group B's latencies hide under group A's
// compute and vice versa (T15 pattern). One barrier per step covers both.
// MFMA accumulate back to 3-deep chains (R10's split added VALU for nothing).
// Per step per wave: 6 ds_read_b128 (issued first), 2 x-stage/prefetch,
// 24 MFMA (8 indep chains), 2 activations, 2 h-writes, lgkmcnt(0)+s_barrier.
// Layout per group unchanged from R9b: z[4,64cols]=[h|x][4,96]f16 @ W f16,
// A rows replicated 4x via LDS broadcast -> C reg0 = all 4 gates of one
// (seq=l>>4, unit=16w+(l&15)) cell in-register.

#define VOCAB 50000
#define EMB 32
#define HID 64
#define NCLS 3
#define BATCH 512
#define TSEQ 512
#define FOURH 256
#define LOG2E 1.4426950408889634f
#define GSEQ 8
#define NBLK (BATCH / GSEQ)
#define GSTRIDE 1536   // bytes: one group's hx[2][4][96] fp16

typedef _Float16 half8 __attribute__((ext_vector_type(8)));
typedef float f32x4 __attribute__((ext_vector_type(4)));

#define MFMA16 __builtin_amdgcn_mfma_f32_16x16x32_f16
#define PKRTZ(a, b) __builtin_bit_cast(int, __builtin_amdgcn_cvt_pkrtz((a), (b)))

// h/x LDS writes drained for cross-wave visibility; global loads uncounted.
#define WAVE_BARRIER()                                        \
    {                                                         \
        asm volatile("s_waitcnt lgkmcnt(0)" ::: "memory");    \
        __builtin_amdgcn_s_barrier();                         \
    }

#define ACT(zi, zf, zg, zo, cst, hv)                                          \
    {                                                                         \
        const float si = __builtin_amdgcn_rcpf(                               \
            1.0f + __builtin_amdgcn_exp2f(fmaf(zi, -LOG2E, bci)));            \
        const float sf = __builtin_amdgcn_rcpf(                               \
            1.0f + __builtin_amdgcn_exp2f(fmaf(zf, -LOG2E, bcf)));            \
        const float sg = __builtin_amdgcn_rcpf(                               \
            1.0f + __builtin_amdgcn_exp2f(fmaf(zg, -2.0f * LOG2E, bcg)));     \
        const float so = __builtin_amdgcn_rcpf(                               \
            1.0f + __builtin_amdgcn_exp2f(fmaf(zo, -LOG2E, bco)));            \
        const float gt = fmaf(2.0f, sg, -1.0f);                               \
        cst = fmaf(sf, cst, si * gt);                                         \
        const float st2 = __builtin_amdgcn_rcpf(                              \
            1.0f + __builtin_amdgcn_exp2f(cst * (-2.0f * LOG2E)));            \
        hv = so * fmaf(2.0f, st2, -1.0f);                                     \
    }

// One LSTM step advancing BOTH groups. CUR = buffer parity, TT = timestep.
// XWA/XWB hold x(TT+1) (stored to buf nxt now); XLA/XLB receive x(TT+2).
#define LSTM_STEP(CUR, TT, XWA, XLA, XWB, XLB)                                \
    {                                                                         \
        const half8* apA = (const half8*)(hxc + (CUR) * 768 + abase);         \
        const half8 a0A = apA[0];                                             \
        const half8 a1A = apA[4];                                             \
        const half8 a2A = apA[8];                                             \
        const half8* apB = (const half8*)(hxc + GSTRIDE + (CUR) * 768 + abase);\
        const half8 a0B = apB[0];                                             \
        const half8 a1B = apB[4];                                             \
        const half8 a2B = apB[8];                                             \
        const int tn2 = ((TT) + 2 < TSEQ) ? (TT) + 2 : TSEQ - 1;              \
        if (l < 8) {                                                          \
            int2 st;                                                          \
            st.x = PKRTZ(XWA.x, XWA.y);                                       \
            st.y = PKRTZ(XWA.z, XWA.w);                                       \
            *(int2*)(hxc + ((CUR) ^ 1) * 768 + xwoff) = st;                   \
            const int tk = toks[(w << 9) + tn2];                              \
            XLA = *(const float4*)(emb + tk * EMB + ((l & 7) << 2));          \
        } else if (l < 16) {                                                  \
            int2 st;                                                          \
            st.x = PKRTZ(XWB.x, XWB.y);                                       \
            st.y = PKRTZ(XWB.z, XWB.w);                                       \
            *(int2*)(hxc + GSTRIDE + ((CUR) ^ 1) * 768 + xwoffB) = st;        \
            const int tk = toks[((4 + w) << 9) + tn2];                        \
            XLB = *(const float4*)(emb + tk * EMB + ((l & 7) << 2));          \
        }                                                                     \
        f32x4 zA0, zA1, zA2, zA3, zB0, zB1, zB2, zB3;                         \
        zA0 = MFMA16(a0A, bfr[0][0], zz, 0, 0, 0);                            \
        zA1 = MFMA16(a0A, bfr[1][0], zz, 0, 0, 0);                            \
        zA2 = MFMA16(a0A, bfr[2][0], zz, 0, 0, 0);                            \
        zA3 = MFMA16(a0A, bfr[3][0], zz, 0, 0, 0);                            \
        zB0 = MFMA16(a0B, bfr[0][0], zz, 0, 0, 0);                            \
        zB1 = MFMA16(a0B, bfr[1][0], zz, 0, 0, 0);                            \
        zB2 = MFMA16(a0B, bfr[2][0], zz, 0, 0, 0);                            \
        zB3 = MFMA16(a0B, bfr[3][0], zz, 0, 0, 0);                            \
        zA0 = MFMA16(a1A, bfr[0][1], zA0, 0, 0, 0);                           \
        zA1 = MFMA16(a1A, bfr[1][1], zA1, 0, 0, 0);                           \
        zA2 = MFMA16(a1A, bfr[2][1], zA2, 0, 0, 0);                           \
        zA3 = MFMA16(a1A, bfr[3][1], zA3, 0, 0, 0);                           \
        zB0 = MFMA16(a1B, bfr[0][1], zB0, 0, 0, 0);                           \
        zB1 = MFMA16(a1B, bfr[1][1], zB1, 0, 0, 0);                           \
        zB2 = MFMA16(a1B, bfr[2][1], zB2, 0, 0, 0);                           \
        zB3 = MFMA16(a1B, bfr[3][1], zB3, 0, 0, 0);                           \
        zA0 = MFMA16(a2A, bfr[0][2], zA0, 0, 0, 0);                           \
        zA1 = MFMA16(a2A, bfr[1][2], zA1, 0, 0, 0);                           \
        zA2 = MFMA16(a2A, bfr[2][2], zA2, 0, 0, 0);                           \
        zA3 = MFMA16(a2A, bfr[3][2], zA3, 0, 0, 0);                           \
        zB0 = MFMA16(a2B, bfr[0][2], zB0, 0, 0, 0);                           \
        zB1 = MFMA16(a2B, bfr[1][2], zB1, 0, 0, 0);                           \
        zB2 = MFMA16(a2B, bfr[2][2], zB2, 0, 0, 0);                           \
        zB3 = MFMA16(a2B, bfr[3][2], zB3, 0, 0, 0);                           \
        float hvA, hvB;                                                       \
        ACT(zA0[0], zA1[0], zA2[0], zA3[0], cstA, hvA)                        \
        ACT(zB0[0], zB1[0], zB2[0], zB3[0], cstB, hvB)                        \
        *(_Float16*)(hxc + ((CUR) ^ 1) * 768 + hwoff) = (_Float16)hvA;        \
        *(_Float16*)(hxc + GSTRIDE + ((CUR) ^ 1) * 768 + hwoff) = (_Float16)hvB;\
        WAVE_BARRIER()                                                        \
    }

__global__ __launch_bounds__(256)
void lstm_kernel(const int* __restrict__ tokens, const float* __restrict__ emb,
                 const float* __restrict__ Wk, const float* __restrict__ Wr,
                 const float* __restrict__ bias, const float* __restrict__ Wd,
                 const float* __restrict__ bd, float* __restrict__ out)
{
    // Two groups: [group][buf][seq][k]; k 0..63 = h, 64..95 = x (fp16).
    __shared__ __align__(16) _Float16 hx[2][2][4][96];
    __shared__ int toks[GSEQ * TSEQ];

    const int tid = threadIdx.x;
    const int w   = tid >> 6;          // wave 0..3 -> unit slice [16w,16w+16)
    const int l   = tid & 63;
    const int li  = l & 15;
    const int q   = l >> 4;            // seq id (within group) / k-subchunk
    const int s0  = blockIdx.x << 3;   // first sequence of this block

    char* hxc = (char*)&hx[0][0][0][0];

    // ---- stage all 4096 tokens (16 KB contiguous) ----
    {
        const int4* src = (const int4*)(tokens + ((long)s0 << 9));
        int4* dst = (int4*)toks;
        dst[tid]       = src[tid];
        dst[tid + 256] = src[tid + 256];
        dst[tid + 512] = src[tid + 512];
        dst[tid + 768] = src[tid + 768];
    }

    // ---- zero h-region of buffer 0, both groups ----
    if (tid < 128) {
        int2 z2; z2.x = 0; z2.y = 0;
        *(int2*)(hxc + (tid >> 6) * GSTRIDE + (((tid >> 4) & 3) * 192) +
                 ((tid & 15) << 3)) = z2;
    }

    // ---- persistent fp16 weight fragments (shared by both groups):
    //      B[k, col], col = 64g + 16w + li, k = 32*c2 + 8*q + i.
    //      Rows 0..63 = Wr, 64..95 = Wk. ----
    half8 bfr[4][3];
#pragma unroll
    for (int g = 0; g < 4; ++g) {
        const int col = (g << 6) + (w << 4) + li;
#pragma unroll
        for (int c2 = 0; c2 < 3; ++c2) {
#pragma unroll
            for (int i = 0; i < 8; ++i) {
                const int k = (c2 << 5) + (q << 3) + i;
                const float wv = (k < HID) ? Wr[k * FOURH + col]
                                           : Wk[(k - HID) * FOURH + col];
                bfr[g][c2][i] = (_Float16)wv;
            }
        }
    }

    // ---- activation constants (bias folded into exp2 argument) ----
    const int u = (w << 4) + li;
    const float bci = -bias[u] * LOG2E;
    const float bcf = -bias[u + 64] * LOG2E;
    const float bcg = -bias[u + 128] * (2.0f * LOG2E);
    const float bco = -bias[u + 192] * LOG2E;

    // ---- per-lane LDS byte offsets ----
    const int abase  = ((li >> 2) * 192) + (q << 4);  // A-frag base (row bcast)
    const int hwoff  = q * 192 + (u << 1);            // h write: [seq=q][u]
    const int xwoff  = w * 192 + 128 + ((l & 7) << 3);    // x write grp A
    const int xwoffB = w * 192 + 128 + ((l & 7) << 3);    // x write grp B

    __syncthreads();   // toks + zeroed h visible (one-time full drain ok)

    // ---- stage x(0) both groups; preload x(1) ----
    float4 xA1 = make_float4(0.f, 0.f, 0.f, 0.f);
    float4 xA2 = make_float4(0.f, 0.f, 0.f, 0.f);
    float4 xB1 = make_float4(0.f, 0.f, 0.f, 0.f);
    float4 xB2 = make_float4(0.f, 0.f, 0.f, 0.f);
    if (l < 8) {
        const int tk0 = toks[w << 9];
        const float4 x0 = *(const float4*)(emb + tk0 * EMB + ((l & 7) << 2));
        int2 st;
        st.x = PKRTZ(x0.x, x0.y);
        st.y = PKRTZ(x0.z, x0.w);
        *(int2*)(hxc + xwoff) = st;
        const int tk1 = toks[(w << 9) + 1];
        xA1 = *(const float4*)(emb + tk1 * EMB + ((l & 7) << 2));
    } else if (l < 16) {
        const int tk0 = toks[(4 + w) << 9];
        const float4 x0 = *(const float4*)(emb + tk0 * EMB + ((l & 7) << 2));
        int2 st;
        st.x = PKRTZ(x0.x, x0.y);
        st.y = PKRTZ(x0.z, x0.w);
        *(int2*)(hxc + GSTRIDE + xwoffB) = st;
        const int tk1 = toks[((4 + w) << 9) + 1];
        xB1 = *(const float4*)(emb + tk1 * EMB + ((l & 7) << 2));
    }
    __syncthreads();

    float cstA = 0.0f, cstB = 0.0f;
    const f32x4 zz = {0.0f, 0.0f, 0.0f, 0.0f};

    for (int t = 0; t < TSEQ; t += 2) {
        LSTM_STEP(0, t,     xA1, xA2, xB1, xB2)
        LSTM_STEP(1, t + 1, xA2, xA1, xB2, xB1)
    }

    // ---- epilogue: final h in buf 0 of each group. Dense(3) + softmax. ----
    if (tid < GSEQ) {
        const _Float16* hf =
            (const _Float16*)(hxc + (tid >> 2) * GSTRIDE + (tid & 3) * 192);
        float a0 = bd[0], a1 = bd[1], a2 = bd[2];
#pragma unroll 8
        for (int k = 0; k < HID; ++k) {
            const float hk = (float)hf[k];
            a0 = fmaf(hk, Wd[k * NCLS + 0], a0);
            a1 = fmaf(hk, Wd[k * NCLS + 1], a1);
            a2 = fmaf(hk, Wd[k * NCLS + 2], a2);
        }
        const float mm = fmaxf(a0, fmaxf(a1, a2));
        const float e0 = __expf(a0 - mm);
        const float e1 = __expf(a1 - mm);
        const float e2 = __expf(a2 - mm);
        const float den = e0 + e1 + e2;
        float* op = out + (s0 + tid) * NCLS;
        op[0] = e0 / den;
        op[1] = e1 / den;
        op[2] = e2 / den;
    }
}

extern "C" void kernel_launch(void* const* d_in, const int* in_sizes, int n_in,
                              void* d_out, int out_size, void* d_ws, size_t ws_size,
                              hipStream_t stream) {
    const int*   tokens = (const int*)  d_in[0];
    const float* emb    = (const float*)d_in[1];
    const float* Wk     = (const float*)d_in[2];
    const float* Wr     = (const float*)d_in[3];
    const float* b      = (const float*)d_in[4];
    const float* Wd     = (const float*)d_in[5];
    const float* bd     = (const float*)d_in[6];
    float* out = (float*)d_out;
    (void)d_ws; (void)ws_size; (void)in_sizes; (void)n_in; (void)out_size;

    lstm_kernel<<<dim3(NBLK), dim3(256), 0, stream>>>(
        tokens, emb, Wk, Wr, b, Wd, bd, out);
}

// Round 5
// 279.445 us; speedup vs baseline: 1.6005x; 1.6005x over previous
//
#include <hip/hip_runtime.h>

// R12: shrink the per-wave serial chain. R11 post-mortem: barrier-synced
// waves run in lockstep, so adding a second group per wave doubled the chain
// (fully serialized, 2.2x regression). The step-time floor is the per-wave
// chain: A-wait ~120 + MFMA issue (12 x ~17 cyc on one SIMD) + ACT ~130 +
// drain/barrier. Fix: split 256 cols over 8 waves (512 thr) instead of 4 ->
// 6 MFMAs/wave (2 col-tiles x 3 K-chunks, two independent 3-chains). Each
// wave owns 8 units x 4 gates; a lane holds 2 gates (tile0={i,f},
// tile1={g,o}); partner lane l^8 holds the other 2 -> one ds_swizzle xor-8
// pair exchanges them; both partners run the full (validated R9b) ACT
// redundantly. Back to __syncthreads (R10 raw barrier was neutral/worse).
// Layout per block unchanged: 4 seqs, z[4,256] = [h|x][4,96]f16 @ W f16,
// A rows replicated 4x via LDS broadcast; C reg0 = (seq=l>>4, own col).

#define VOCAB 50000
#define EMB 32
#define HID 64
#define NCLS 3
#define BATCH 512
#define TSEQ 512
#define FOURH 256
#define LOG2E 1.4426950408889634f
#define GSEQ 4
#define NBLK (BATCH / GSEQ)

typedef _Float16 half8 __attribute__((ext_vector_type(8)));
typedef float f32x4 __attribute__((ext_vector_type(4)));

#define MFMA16 __builtin_amdgcn_mfma_f32_16x16x32_f16
#define PKRTZ(a, b) __builtin_bit_cast(int, __builtin_amdgcn_cvt_pkrtz((a), (b)))
#define SWZ_XOR8 0x201F   // BitMode: xor_mask=8, and_mask=0x1F

__device__ __forceinline__ float swz8(float x) {
    return __builtin_bit_cast(float,
        __builtin_amdgcn_ds_swizzle(__builtin_bit_cast(int, x), SWZ_XOR8));
}

// One LSTM step. CUR = buffer parity, TT = timestep. XW holds x(TT+1)
// (stored to buf nxt now); XL receives x(TT+2). stg = staging lane.
#define LSTM_STEP(CUR, TT, XW, XL)                                            \
    {                                                                         \
        const half8* ap = (const half8*)(hxc + (CUR) * 768 + abase);          \
        const half8 a0 = ap[0];                                               \
        const half8 a1 = ap[4];                                               \
        const half8 a2 = ap[8];                                               \
        if (stg) {                                                            \
            int2 st;                                                          \
            st.x = PKRTZ(XW.x, XW.y);                                         \
            st.y = PKRTZ(XW.z, XW.w);                                         \
            *(int2*)(hxc + ((CUR) ^ 1) * 768 + xwoff) = st;                   \
        }                                                                     \
        f32x4 t0, t1;                                                         \
        t0 = MFMA16(a0, bfr[0][0], zz, 0, 0, 0);                              \
        t1 = MFMA16(a0, bfr[1][0], zz, 0, 0, 0);                              \
        t0 = MFMA16(a1, bfr[0][1], t0, 0, 0, 0);                              \
        t1 = MFMA16(a1, bfr[1][1], t1, 0, 0, 0);                              \
        t0 = MFMA16(a2, bfr[0][2], t0, 0, 0, 0);                              \
        t1 = MFMA16(a2, bfr[1][2], t1, 0, 0, 0);                              \
        if (stg) {                                                            \
            const int tn2 = ((TT) + 2 < TSEQ) ? (TT) + 2 : TSEQ - 1;          \
            const int tk = toks[(w << 9) + tn2];                              \
            XL = *(const float4*)(emb + tk * EMB + (l << 2));                 \
        }                                                                     \
        const float own0 = t0[0], own1 = t1[0];                               \
        const float oth0 = swz8(own0);                                        \
        const float oth1 = swz8(own1);                                        \
        const float zi = b3 ? oth0 : own0;                                    \
        const float zf = b3 ? own0 : oth0;                                    \
        const float zg = b3 ? oth1 : own1;                                    \
        const float zo = b3 ? own1 : oth1;                                    \
        const float si = __builtin_amdgcn_rcpf(                               \
            1.0f + __builtin_amdgcn_exp2f(fmaf(zi, -LOG2E, bci)));            \
        const float sf = __builtin_amdgcn_rcpf(                               \
            1.0f + __builtin_amdgcn_exp2f(fmaf(zf, -LOG2E, bcf)));            \
        const float sg = __builtin_amdgcn_rcpf(                               \
            1.0f + __builtin_amdgcn_exp2f(fmaf(zg, -2.0f * LOG2E, bcg)));     \
        const float so = __builtin_amdgcn_rcpf(                               \
            1.0f + __builtin_amdgcn_exp2f(fmaf(zo, -LOG2E, bco)));            \
        const float gt = fmaf(2.0f, sg, -1.0f);                               \
        cst = fmaf(sf, cst, si * gt);                                         \
        const float st2 = __builtin_amdgcn_rcpf(                              \
            1.0f + __builtin_amdgcn_exp2f(cst * (-2.0f * LOG2E)));            \
        const float hv = so * fmaf(2.0f, st2, -1.0f);                         \
        if (!b3) *(_Float16*)(hxc + ((CUR) ^ 1) * 768 + hwoff) = (_Float16)hv;\
        __syncthreads();                                                      \
    }

__global__ __launch_bounds__(512)
void lstm_kernel(const int* __restrict__ tokens, const float* __restrict__ emb,
                 const float* __restrict__ Wk, const float* __restrict__ Wr,
                 const float* __restrict__ bias, const float* __restrict__ Wd,
                 const float* __restrict__ bd, float* __restrict__ out)
{
    // [buf][seq][k]: k 0..63 = h (fp16), k 64..95 = x (fp16). Row = 192 B.
    __shared__ __align__(16) _Float16 hx[2][GSEQ][96];
    __shared__ int toks[GSEQ * TSEQ];

    const int tid = threadIdx.x;
    const int w   = tid >> 6;          // wave 0..7 -> unit slice [8w, 8w+8)
    const int l   = tid & 63;
    const int li  = l & 15;
    const int q   = l >> 4;            // seq id (reg0) / k-subchunk id
    const int b3  = (l >> 3) & 1;      // gate-pair selector (0:{i,g} 1:{f,o})
    const bool stg = (w < 4) && (l < 8);   // x-staging lanes (wave w: seq w)
    const int s0  = blockIdx.x << 2;   // first sequence of this block

    char* hxc = (char*)&hx[0][0][0];

    // ---- stage all 2048 tokens (8 KB, one int4 per thread) ----
    {
        const int4* src = (const int4*)(tokens + ((long)s0 << 9));
        ((int4*)toks)[tid] = src[tid];
    }

    // ---- zero h-region of buffer 0 (4 rows x 128 B) ----
    if (tid < 64) {
        int2 z2; z2.x = 0; z2.y = 0;
        *(int2*)(hxc + (tid >> 4) * 192 + ((tid & 15) << 3)) = z2;
    }

    // ---- persistent fp16 weight fragments: 2 col-tiles x 3 K-chunks.
    //      Tile tau col ci=li -> unit 8w+(ci&7), gate 2*tau+(ci>>3);
    //      W col = 64*gate + unit. k = 32*c2 + 8*q + i; rows 0..63 = Wr,
    //      64..95 = Wk. ----
    half8 bfr[2][3];
#pragma unroll
    for (int tau = 0; tau < 2; ++tau) {
        const int gate = (tau << 1) + (li >> 3);
        const int col = (gate << 6) + (w << 3) + (li & 7);
#pragma unroll
        for (int c2 = 0; c2 < 3; ++c2) {
#pragma unroll
            for (int i = 0; i < 8; ++i) {
                const int k = (c2 << 5) + (q << 3) + i;
                const float wv = (k < HID) ? Wr[k * FOURH + col]
                                           : Wk[(k - HID) * FOURH + col];
                bfr[tau][c2][i] = (_Float16)wv;
            }
        }
    }

    // ---- activation constants for this lane's unit (all 4 gates) ----
    const int u = (w << 3) + (l & 7);
    const float bci = -bias[u] * LOG2E;
    const float bcf = -bias[u + 64] * LOG2E;
    const float bcg = -bias[u + 128] * (2.0f * LOG2E);
    const float bco = -bias[u + 192] * LOG2E;

    // ---- per-lane LDS byte offsets ----
    const int abase = ((li >> 2) * 192) + (q << 4);   // A-frag base (row bcast)
    const int hwoff = (l >> 4) * 192 + (u << 1);      // h write: [seq=l>>4][u]
    const int xwoff = w * 192 + 128 + (l << 3);       // x write: [seq=w][64+..]

    __syncthreads();   // toks + zeroed h visible

    // ---- stage x(0) into buf0; preload xA = x(1) ----
    float4 xA = make_float4(0.f, 0.f, 0.f, 0.f);
    float4 xB = make_float4(0.f, 0.f, 0.f, 0.f);
    if (stg) {
        const int tk0 = toks[w << 9];
        const float4 x0 = *(const float4*)(emb + tk0 * EMB + (l << 2));
        int2 st;
        st.x = PKRTZ(x0.x, x0.y);
        st.y = PKRTZ(x0.z, x0.w);
        *(int2*)(hxc + xwoff) = st;
        const int tk1 = toks[(w << 9) + 1];
        xA = *(const float4*)(emb + tk1 * EMB + (l << 2));
    }
    __syncthreads();

    float cst = 0.0f;
    const f32x4 zz = {0.0f, 0.0f, 0.0f, 0.0f};

    for (int t = 0; t < TSEQ; t += 2) {
        LSTM_STEP(0, t, xA, xB)
        LSTM_STEP(1, t + 1, xB, xA)
    }

    // ---- epilogue: final h is in hx[0] (T even). Dense(3) + softmax. ----
    if (tid < GSEQ) {
        const _Float16* hf = &hx[0][tid][0];
        float a0 = bd[0], a1 = bd[1], a2 = bd[2];
#pragma unroll 8
        for (int k = 0; k < HID; ++k) {
            const float hk = (float)hf[k];
            a0 = fmaf(hk, Wd[k * NCLS + 0], a0);
            a1 = fmaf(hk, Wd[k * NCLS + 1], a1);
            a2 = fmaf(hk, Wd[k * NCLS + 2], a2);
        }
        const float mm = fmaxf(a0, fmaxf(a1, a2));
        const float e0 = __expf(a0 - mm);
        const float e1 = __expf(a1 - mm);
        const float e2 = __expf(a2 - mm);
        const float den = e0 + e1 + e2;
        float* op = out + (s0 + tid) * NCLS;
        op[0] = e0 / den;
        op[1] = e1 / den;
        op[2] = e2 / den;
    }
}

extern "C" void kernel_launch(void* const* d_in, const int* in_sizes, int n_in,
                              void* d_out, int out_size, void* d_ws, size_t ws_size,
                              hipStream_t stream) {
    const int*   tokens = (const int*)  d_in[0];
    const float* emb    = (const float*)d_in[1];
    const float* Wk     = (const float*)d_in[2];
    const float* Wr     = (const float*)d_in[3];
    const float* b      = (const float*)d_in[4];
    const float* Wd     = (const float*)d_in[5];
    const float* bd     = (const float*)d_in[6];
    float* out = (float*)d_out;
    (void)d_ws; (void)ws_size; (void)in_sizes; (void)n_in; (void)out_size;

    lstm_kernel<<<dim3(NBLK), dim3(512), 0, stream>>>(
        tokens, emb, Wk, Wr, b, Wd, bd, out);
}